// Round 16
// baseline (117.438 us; speedup 1.0000x reference)
//
#include <hip/hip_runtime.h>
#include <cstdint>
#include <cstddef>

#define C_DIM 256
#define N_PIX 10000
#define B_SZ 16

// ---------------- k_prep_wpe (R15-exact) ------------------------------------------------
__global__ __launch_bounds__(256) void k_prep_wpe(
    const float* __restrict__ pe,
    const float* __restrict__ Wc, const float* __restrict__ Wb,
    float* __restrict__ wpe) {
  int tid = threadIdx.x;
  int bid = blockIdx.x;                 // 60 blocks
  int o = bid / 10;
  int p = (bid % 10) * 256 + tid;
  if (p >= 2500) return;
  const float* W = (o < 2) ? (Wc + o * C_DIM) : (Wb + (o - 2) * C_DIM);
  float acc = 0.f;
#pragma unroll 8
  for (int c = 0; c < C_DIM; ++c) acc = fmaf(W[c], pe[c * 2500 + p], acc);
  wpe[o * 2500 + p] = acc;
}

// ---------------- k_heads4 (R15-exact) --------------------------------------------------
__global__ __launch_bounds__(256, 4) void k_heads4(
    const float* __restrict__ x, const float* __restrict__ wpe,
    const float* __restrict__ Wc, const float* __restrict__ bc,
    const float* __restrict__ Wb, const float* __restrict__ bb,
    float* __restrict__ cls, float* __restrict__ bbox, float* __restrict__ conf) {
  int tid = threadIdx.x;
  int b = blockIdx.y;
  int n = blockIdx.x * 256 + tid;
  if (n >= N_PIX) return;
  const float* xb = x + (size_t)b * C_DIM * N_PIX + n;
  const float* w1p = Wc + C_DIM;
  const float* w2p = Wb;
  const float* w3p = Wb + C_DIM;
  const float* w4p = Wb + 2 * C_DIM;
  const float* w5p = Wb + 3 * C_DIM;
  float a0 = 0.f, a1 = 0.f, a2 = 0.f, a3 = 0.f, a4 = 0.f, a5 = 0.f;
  for (int c = 0; c < C_DIM; c += 16) {
    float xv[16];
#pragma unroll
    for (int j = 0; j < 16; ++j) xv[j] = xb[(size_t)(c + j) * N_PIX];
#pragma unroll
    for (int j = 0; j < 16; ++j) {
      float v = xv[j];
      a0 = fmaf(Wc[c + j],  v, a0);
      a1 = fmaf(w1p[c + j], v, a1);
      a2 = fmaf(w2p[c + j], v, a2);
      a3 = fmaf(w3p[c + j], v, a3);
      a4 = fmaf(w4p[c + j], v, a4);
      a5 = fmaf(w5p[c + j], v, a5);
    }
  }
  int y = n / 100, xq = n % 100;
  float sy = fminf(fmaxf((y + 0.5f) * 0.5f - 0.5f, 0.0f), 49.0f);
  float sx = fminf(fmaxf((xq + 0.5f) * 0.5f - 0.5f, 0.0f), 49.0f);
  int y0 = (int)floorf(sy); int y1 = min(y0 + 1, 49); float ty = sy - (float)y0;
  int x0i = (int)floorf(sx); int x1i = min(x0i + 1, 49); float tx = sx - (float)x0i;
  float pd[6];
#pragma unroll
  for (int o = 0; o < 6; ++o) {
    const float* m = wpe + o * 2500;
    float v00 = m[y0 * 50 + x0i], v01 = m[y0 * 50 + x1i];
    float v10 = m[y1 * 50 + x0i], v11 = m[y1 * 50 + x1i];
    float r0 = v00 * (1.0f - ty) + v10 * ty;
    float r1 = v01 * (1.0f - ty) + v11 * ty;
    pd[o] = r0 * (1.0f - tx) + r1 * tx;
  }
  float c0 = a0 + pd[0] + bc[0];
  float c1 = a1 + pd[1] + bc[1];
  float b0 = a2 + pd[2] + bb[0];
  float b1 = a3 + pd[3] + bb[1];
  float b2 = a4 + pd[4] + bb[2];
  float b3 = a5 + pd[5] + bb[3];
  size_t nb = (size_t)b * N_PIX + n;
  float2 cv; cv.x = c0; cv.y = c1;
  *(float2*)(cls + nb * 2) = cv;
  float4 bv; bv.x = b0; bv.y = b1; bv.z = b2; bv.w = b3;
  *(float4*)(bbox + nb * 4) = bv;
  float m0 = fmaxf(c0, c1);
  float e0 = expf(c0 - m0), e1 = expf(c1 - m0);
  conf[nb] = e1 / (e0 + e1);
}

// ---------------- topk phase 1 (blocks 0..127) + wT transpose (128..223) ----------------
// phase1: per-(batch,chunk of 1250) local top>=100 threshold, emit candidate keys.
__global__ __launch_bounds__(256) void k_topk1p(
    const float* __restrict__ conf,
    unsigned long long* __restrict__ candbuf, unsigned int* __restrict__ cntbuf,
    const float* __restrict__ dW1, const float* __restrict__ dW2, const float* __restrict__ dW3,
    const float* __restrict__ rW1, const float* __restrict__ rW2, const float* __restrict__ rW3,
    float* __restrict__ wT) {
  int tid = threadIdx.x;
  int bid = blockIdx.x;
  if (bid >= 128) {
    __shared__ float tile[64][65];
    int t = bid - 128;                // 96 blocks: 6 matrices x 16 (64x64) tiles
    int m = t >> 4;
    int tl = t & 15;
    int ty = tl >> 2, tx = tl & 3;
    const float* W;
    switch (m) {
      case 0: W = dW1; break;
      case 1: W = dW2; break;
      case 2: W = dW3; break;
      case 3: W = rW1; break;
      case 4: W = rW2; break;
      default: W = rW3; break;
    }
    int lane = tid & 63, rg = tid >> 6;
    for (int rr = rg; rr < 64; rr += 4)
      tile[rr][lane] = W[(size_t)(ty * 64 + rr) * 256 + tx * 64 + lane];
    __syncthreads();
    for (int rr = rg; rr < 64; rr += 4)
      wT[(size_t)m * 65536 + (size_t)(tx * 64 + rr) * 256 + ty * 64 + lane] = tile[lane][rr];
    return;
  }
  __shared__ unsigned int ordl[1250];
  __shared__ unsigned int whist[4][256];
  __shared__ unsigned int sfx[256];
  __shared__ unsigned int s_cnt, s_prefix, s_nc;
  int wv = tid >> 6;
  int b = bid >> 3, chunk = bid & 7;
  int base = chunk * 1250;
  const float* cb = conf + (size_t)b * N_PIX + base;
  for (int i = tid; i < 1250; i += 256) {
    unsigned int u = __float_as_uint(cb[i]);
    ordl[i] = (u & 0x80000000u) ? ~u : (u | 0x80000000u);
  }
  unsigned int prefix = 0, cnt_gt = 0;
  for (int pass = 0; pass < 4; ++pass) {
    int sh = 24 - 8 * pass;
    for (int i = tid; i < 4 * 256; i += 256) ((unsigned int*)whist)[i] = 0;
    __syncthreads();
    unsigned int himask = (pass == 0) ? 0u : (0xFFFFFFFFu << (sh + 8));
    for (int i = tid; i < 1250; i += 256) {
      unsigned int o = ordl[i];
      if ((o & himask) == prefix) atomicAdd(&whist[wv][(o >> sh) & 255u], 1u);
    }
    __syncthreads();
    sfx[tid] = whist[0][tid] + whist[1][tid] + whist[2][tid] + whist[3][tid];
    __syncthreads();
#pragma unroll
    for (int off = 1; off < 256; off <<= 1) {
      unsigned int add = 0;
      if (tid + off < 256) add = sfx[tid + off];
      __syncthreads();
      sfx[tid] += add;
      __syncthreads();
    }
    {
      unsigned int Sv = sfx[tid];
      unsigned int Sn = (tid < 255) ? sfx[tid + 1] : 0u;
      if (cnt_gt + Sv >= 100u && (tid == 255 || cnt_gt + Sn < 100u)) {
        s_cnt = cnt_gt + Sn;
        s_prefix = prefix | ((unsigned int)tid << sh);
      }
    }
    __syncthreads();
    cnt_gt = s_cnt; prefix = s_prefix;
    __syncthreads();
  }
  if (tid == 0) s_nc = 0;
  __syncthreads();
  unsigned int T = prefix;
  unsigned long long* cb_out = candbuf + (size_t)(b * 8 + chunk) * 512;
  for (int i = tid; i < 1250; i += 256) {
    unsigned int o = ordl[i];
    if (o >= T) {
      unsigned int k = atomicAdd(&s_nc, 1u);
      if (k < 512u)
        cb_out[k] = ((unsigned long long)o << 32) |
                    (unsigned long long)(0xFFFFFFFFu - (unsigned int)(base + i));
    }
  }
  __syncthreads();
  if (tid == 0) cntbuf[b * 8 + chunk] = s_nc > 512u ? 512u : s_nc;
}

// ---------------- topk phase 2: merge 8 chunks' candidates -> top-100 -------------------
__global__ __launch_bounds__(256) void k_topk2(
    const unsigned long long* __restrict__ candbuf, const unsigned int* __restrict__ cntbuf,
    int* __restrict__ idx_out) {
  __shared__ unsigned long long keys[4096];
  __shared__ unsigned int whist[4][256];
  __shared__ unsigned int sfx[256];
  __shared__ unsigned long long cand2[256];
  __shared__ unsigned int s_cnt, s_prefix, s_nc;
  int tid = threadIdx.x;
  int wv = tid >> 6;
  int b = blockIdx.x;
  for (int s = tid; s < 4096; s += 256) {
    int ci = s >> 9, i = s & 511;
    unsigned int c = cntbuf[b * 8 + ci];
    keys[s] = ((unsigned int)i < c) ? candbuf[(size_t)(b * 8 + ci) * 512 + i] : 0ull;
  }
  __syncthreads();
  unsigned int prefix = 0, cnt_gt = 0;
  for (int pass = 0; pass < 4; ++pass) {
    int sh = 24 - 8 * pass;
    for (int i = tid; i < 4 * 256; i += 256) ((unsigned int*)whist)[i] = 0;
    __syncthreads();
    unsigned int himask = (pass == 0) ? 0u : (0xFFFFFFFFu << (sh + 8));
    for (int s = tid; s < 4096; s += 256) {
      unsigned int o = (unsigned int)(keys[s] >> 32);
      if ((o & himask) == prefix) atomicAdd(&whist[wv][(o >> sh) & 255u], 1u);
    }
    __syncthreads();
    sfx[tid] = whist[0][tid] + whist[1][tid] + whist[2][tid] + whist[3][tid];
    __syncthreads();
#pragma unroll
    for (int off = 1; off < 256; off <<= 1) {
      unsigned int add = 0;
      if (tid + off < 256) add = sfx[tid + off];
      __syncthreads();
      sfx[tid] += add;
      __syncthreads();
    }
    {
      unsigned int Sv = sfx[tid];
      unsigned int Sn = (tid < 255) ? sfx[tid + 1] : 0u;
      if (cnt_gt + Sv >= 100u && (tid == 255 || cnt_gt + Sn < 100u)) {
        s_cnt = cnt_gt + Sn;
        s_prefix = prefix | ((unsigned int)tid << sh);
      }
    }
    __syncthreads();
    cnt_gt = s_cnt; prefix = s_prefix;
    __syncthreads();
  }
  if (tid == 0) s_nc = 0;
  __syncthreads();
  unsigned int T = prefix;
  for (int s = tid; s < 4096; s += 256) {
    unsigned int o = (unsigned int)(keys[s] >> 32);
    if (o >= T) {
      unsigned int k = atomicAdd(&s_nc, 1u);
      if (k < 256u) cand2[k] = keys[s];
    }
  }
  __syncthreads();
  unsigned int nc = s_nc > 256u ? 256u : s_nc;
  if (tid >= (int)nc) cand2[tid] = 0ull;
  __syncthreads();
  for (unsigned int k = 2; k <= 256; k <<= 1) {
    for (unsigned int j = k >> 1; j > 0; j >>= 1) {
      unsigned int i = (unsigned int)tid, ixj = i ^ j;
      if (ixj > i) {
        unsigned long long a = cand2[i], c2 = cand2[ixj];
        bool up = ((i & k) == 0);
        if ((a > c2) == up) { cand2[i] = c2; cand2[ixj] = a; }
      }
      __syncthreads();
    }
  }
  if (tid < 100) {
    unsigned long long key = cand2[255 - tid];
    idx_out[b * 100 + tid] = (int)(0xFFFFFFFFu - (unsigned int)(key & 0xFFFFFFFFull));
  }
}

// ---------------- k_mlp6 (R15-exact) ----------------------------------------------------
#define R8 8

__device__ __forceinline__ float pos_bilinear(const float* __restrict__ pe, int c, int n) {
  int y = n / 100, xq = n % 100;
  float sy = fminf(fmaxf((y + 0.5f) * 0.5f - 0.5f, 0.0f), 49.0f);
  float sx = fminf(fmaxf((xq + 0.5f) * 0.5f - 0.5f, 0.0f), 49.0f);
  int y0 = (int)floorf(sy); int y1 = min(y0 + 1, 49); float ty = sy - (float)y0;
  int x0i = (int)floorf(sx); int x1i = min(x0i + 1, 49); float tx = sx - (float)x0i;
  const float* p = pe + (size_t)c * 2500;
  float v00 = p[y0 * 50 + x0i], v01 = p[y0 * 50 + x1i];
  float v10 = p[y1 * 50 + x0i], v11 = p[y1 * 50 + x1i];
  float rr0 = v00 * (1.0f - ty) + v10 * ty;
  float rr1 = v01 * (1.0f - ty) + v11 * ty;
  return rr0 * (1.0f - tx) + rr1 * tx;
}

__device__ __forceinline__ void mlp6_layer(const float (*in)[C_DIM], float (*outb)[C_DIM],
    float (*red)[R8][C_DIM], const float* __restrict__ Wl, const float* __restrict__ bias,
    bool relu, int og, int rg, int tid) {
  float4 acc[R8];
#pragma unroll
  for (int r = 0; r < R8; ++r) { acc[r].x = 0.f; acc[r].y = 0.f; acc[r].z = 0.f; acc[r].w = 0.f; }
  int c0 = rg * 32;
#pragma unroll 2
  for (int ci = 0; ci < 32; ci += 4) {
    int c = c0 + ci;
    float4 w0 = *(const float4*)(Wl + (size_t)(c + 0) * C_DIM + og * 4);
    float4 w1 = *(const float4*)(Wl + (size_t)(c + 1) * C_DIM + og * 4);
    float4 w2 = *(const float4*)(Wl + (size_t)(c + 2) * C_DIM + og * 4);
    float4 w3 = *(const float4*)(Wl + (size_t)(c + 3) * C_DIM + og * 4);
#pragma unroll
    for (int r = 0; r < R8; ++r) {
      float4 iv = *(const float4*)(&in[r][c]);
      acc[r].x = fmaf(w0.x, iv.x, acc[r].x); acc[r].y = fmaf(w0.y, iv.x, acc[r].y);
      acc[r].z = fmaf(w0.z, iv.x, acc[r].z); acc[r].w = fmaf(w0.w, iv.x, acc[r].w);
      acc[r].x = fmaf(w1.x, iv.y, acc[r].x); acc[r].y = fmaf(w1.y, iv.y, acc[r].y);
      acc[r].z = fmaf(w1.z, iv.y, acc[r].z); acc[r].w = fmaf(w1.w, iv.y, acc[r].w);
      acc[r].x = fmaf(w2.x, iv.z, acc[r].x); acc[r].y = fmaf(w2.y, iv.z, acc[r].y);
      acc[r].z = fmaf(w2.z, iv.z, acc[r].z); acc[r].w = fmaf(w2.w, iv.z, acc[r].w);
      acc[r].x = fmaf(w3.x, iv.w, acc[r].x); acc[r].y = fmaf(w3.y, iv.w, acc[r].y);
      acc[r].z = fmaf(w3.z, iv.w, acc[r].z); acc[r].w = fmaf(w3.w, iv.w, acc[r].w);
    }
  }
#pragma unroll
  for (int r = 0; r < R8; ++r) *(float4*)(&red[rg][r][og * 4]) = acc[r];
  __syncthreads();
#pragma unroll
  for (int k = 0; k < 4; ++k) {
    int e = tid + k * 512;
    int r = e >> 8, o = e & 255;
    float s = bias[o];
#pragma unroll
    for (int g = 0; g < 8; ++g) s += red[g][r][o];
    outb[r][o] = relu ? fmaxf(s, 0.f) : s;
  }
  __syncthreads();
}

__global__ __launch_bounds__(512, 2) void k_mlp6(
    const float* __restrict__ x, const float* __restrict__ pe, const int* __restrict__ idx,
    const float* __restrict__ wT,
    const float* __restrict__ db1, const float* __restrict__ db2, const float* __restrict__ db3,
    const float* __restrict__ rb1, const float* __restrict__ rb2, const float* __restrict__ rb3,
    const float* __restrict__ det_q, const float* __restrict__ rec_q,
    float* __restrict__ det, float* __restrict__ rec) {
  __shared__ float actA[R8][C_DIM];
  __shared__ float actB[R8][C_DIM];
  __shared__ float red[8][R8][C_DIM];
  int tid = threadIdx.x;
  int og = tid & 63, rg = tid >> 6;
  int base = blockIdx.x * R8;
  bool is_det = base < 1600;
  const float *W1, *W2, *W3, *B1, *B2, *B3;
  if (is_det) {
    W1 = wT;          W2 = wT + 65536;  W3 = wT + 131072;
    B1 = db1; B2 = db2; B3 = db3;
  } else {
    W1 = wT + 196608; W2 = wT + 262144; W3 = wT + 327680;
    B1 = rb1; B2 = rb2; B3 = rb3;
  }
#pragma unroll
  for (int k = 0; k < 4; ++k) {
    int e = tid + k * 512;
    int r = e >> 8, c = e & 255;
    int rowid = base + r;
    int b, rr;
    if (rowid < 1600) { b = rowid / 100; rr = rowid % 100; }
    else { int t2 = rowid - 1600; b = t2 / 25; rr = t2 % 25; }
    int n = idx[b * 100 + rr];
    actA[r][c] = x[((size_t)b * C_DIM + c) * N_PIX + n] + pos_bilinear(pe, c, n);
  }
  __syncthreads();
  mlp6_layer(actA, actB, red, W1, B1, true,  og, rg, tid);
  mlp6_layer(actB, actA, red, W2, B2, true,  og, rg, tid);
  mlp6_layer(actA, actB, red, W3, B3, false, og, rg, tid);
#pragma unroll
  for (int k = 0; k < 4; ++k) {
    int e = tid + k * 512;
    int r = e >> 8, o = e & 255;
    int rowid = base + r;
    if (rowid < 1600) {
      int rr = rowid % 100;
      det[(size_t)rowid * C_DIM + o] = actB[r][o] + det_q[rr * C_DIM + o];
    } else {
      int t2 = rowid - 1600; int rr = t2 % 25;
      rec[(size_t)t2 * C_DIM + o] = actB[r][o] + rec_q[rr * C_DIM + o];
    }
  }
}

extern "C" void kernel_launch(void* const* d_in, const int* in_sizes, int n_in,
                              void* d_out, int out_size, void* d_ws, size_t ws_size,
                              hipStream_t stream) {
  const float* x     = (const float*)d_in[0];
  const float* Wc    = (const float*)d_in[1];
  const float* bc    = (const float*)d_in[2];
  const float* Wb    = (const float*)d_in[3];
  const float* bb    = (const float*)d_in[4];
  const float* dW1   = (const float*)d_in[5];
  const float* db1   = (const float*)d_in[6];
  const float* dW2   = (const float*)d_in[7];
  const float* db2   = (const float*)d_in[8];
  const float* dW3   = (const float*)d_in[9];
  const float* db3   = (const float*)d_in[10];
  const float* rW1   = (const float*)d_in[11];
  const float* rb1   = (const float*)d_in[12];
  const float* rW2   = (const float*)d_in[13];
  const float* rb2   = (const float*)d_in[14];
  const float* rW3   = (const float*)d_in[15];
  const float* rb3   = (const float*)d_in[16];
  const float* det_q = (const float*)d_in[17];
  const float* rec_q = (const float*)d_in[18];
  const float* pos_e = (const float*)d_in[19];

  float* out  = (float*)d_out;
  float* det  = out;                // [16,100,256]
  float* rec  = out + 409600;       // [16, 25,256]
  float* cls  = out + 512000;       // [16,10000,2]
  float* bbox = out + 832000;       // [16,10000,4]

  // ws (bytes): wT @0 (1572864) | conf @1572864 (640000) | idx @2212864 (8192)
  //             wpe @2221056 (60000) | candbuf @2281056 (524288) | cnt @2805344 (512)
  char* wsb = (char*)d_ws;
  float* wT   = (float*)wsb;
  float* conf = (float*)(wsb + 1572864);
  int*   idx  = (int*)(wsb + 2212864);
  float* wpe  = (float*)(wsb + 2221056);
  unsigned long long* candbuf = (unsigned long long*)(wsb + 2281056);
  unsigned int* cnt = (unsigned int*)(wsb + 2805344);

  k_prep_wpe<<<60, 256, 0, stream>>>(pos_e, Wc, Wb, wpe);
  k_heads4<<<dim3(40, B_SZ), 256, 0, stream>>>(x, wpe, Wc, bc, Wb, bb, cls, bbox, conf);
  k_topk1p<<<224, 256, 0, stream>>>(conf, candbuf, cnt,
                                    dW1, dW2, dW3, rW1, rW2, rW3, wT);
  k_topk2<<<B_SZ, 256, 0, stream>>>(candbuf, cnt, idx);
  k_mlp6<<<250, 512, 0, stream>>>(x, pos_e, idx, wT,
                                  db1, db2, db3, rb1, rb2, rb3,
                                  det_q, rec_q, det, rec);
}